// Round 1
// baseline (6651.868 us; speedup 1.0000x reference)
//
#include <hip/hip_runtime.h>
#include <math.h>

#define BLK 64
#define NF 32

__device__ __forceinline__ float sigm(float x) {
    return __fdividef(1.0f, 1.0f + __expf(-x));
}
// overflow-safe fast tanh
__device__ __forceinline__ float tanhft(float x) {
    float a = fabsf(x);
    float e = __expf(-2.0f * a);
    float t = __fdividef(1.0f - e, 1.0f + e);
    return copysignf(t, x);
}

// P = F P F^T for the constant-accel F (dt=0.2), in place
__device__ __forceinline__ void fpft(float (&P)[6][6]) {
    const float dt = 0.2f, hd = 0.02f; // dt, dt*dt/2
    #pragma unroll
    for (int j = 0; j < 6; ++j) {       // A = F P (row combine)
        float a0 = P[0][j] + dt * P[1][j] + hd * P[2][j];
        float a1 = P[1][j] + dt * P[2][j];
        float a3 = P[3][j] + dt * P[4][j] + hd * P[5][j];
        float a4 = P[4][j] + dt * P[5][j];
        P[0][j] = a0; P[1][j] = a1; P[3][j] = a3; P[4][j] = a4;
    }
    #pragma unroll
    for (int i = 0; i < 6; ++i) {       // P = A F^T (col combine)
        float a0 = P[i][0] + dt * P[i][1] + hd * P[i][2];
        float a1 = P[i][1] + dt * P[i][2];
        float a3 = P[i][3] + dt * P[i][4] + hd * P[i][5];
        float a4 = P[i][4] + dt * P[i][5];
        P[i][0] = a0; P[i][1] = a1; P[i][3] = a3; P[i][4] = a4;
    }
}

__global__ __launch_bounds__(BLK, 1)
void kalman_lstm(const float* __restrict__ hist,
                 const float* __restrict__ psx, const float* __restrict__ psy,
                 const float* __restrict__ vsx, const float* __restrict__ vsy,
                 const float* __restrict__ asx, const float* __restrict__ asy,
                 const float* __restrict__ jerk, const float* __restrict__ coefG,
                 const float* __restrict__ GRv,
                 const float* __restrict__ cfW, const float* __restrict__ cfb,
                 const float* __restrict__ Wih, const float* __restrict__ Whh,
                 const float* __restrict__ bih, const float* __restrict__ bhh,
                 const float* __restrict__ coW, const float* __restrict__ cob,
                 float* __restrict__ out, int B, int Thist, int len_pred)
{
    // per-thread private LDS columns: [feature][tid] => lane-contiguous, conflict-free
    __shared__ float c_lds[NF][BLK];
    __shared__ float hn_lds[NF][BLK];
    const int tid = threadIdx.x;
    const int b = blockIdx.x * BLK + tid;
    if (b >= B) return;

    const float dt = 0.2f;
    const float hd = 0.02f;                       // dt^2/2
    const float g0 = dt * dt * dt / 6.0f;         // G column entries
    const float g1 = 0.02f;                       // dt^2/2
    const float g2 = dt;

    // uniform precompute (R, G*tanh(coefG), jerk-scaled versions)
    float gr0 = GRv[0], gr1 = GRv[1];
    float R00 = gr0 * gr0, R01 = gr0 * gr1, R11 = gr1 * gr1;
    float ga0 = g0 * tanhf(coefG[0]);
    float ga1 = g1 * tanhf(coefG[1]);
    float ga2 = g2 * tanhf(coefG[2]);
    float gb3 = g0 * tanhf(coefG[3]);
    float gb4 = g1 * tanhf(coefG[4]);
    float gb5 = g2 * tanhf(coefG[5]);
    float j0 = jerk[0], j1 = jerk[1];
    float qa0 = ga0 * j0, qa1 = ga1 * j0, qa2 = ga2 * j0;
    float qb3 = gb3 * j1, qb4 = gb4 * j1, qb5 = gb5 * j1;

    // ---- Kalman init ----
    float z0x = hist[(size_t)b * 2 + 0], z0y = hist[(size_t)b * 2 + 1];
    float z1x = hist[((size_t)B + b) * 2 + 0], z1y = hist[((size_t)B + b) * 2 + 1];
    // NOTE: reference overwrites X[3] (pos-y slot) with v0y — replicate exactly
    float X0 = z0x, X1 = (z1x - z0x) / dt, X2 = 0.0f;
    float X3 = (z1y - z0y) / dt, X4 = 0.0f, X5 = 0.0f;

    float P[6][6];
    #pragma unroll
    for (int i = 0; i < 6; ++i)
        #pragma unroll
        for (int j = 0; j < 6; ++j) P[i][j] = 0.0f;
    { float v;
      v = psx[0]; P[0][0] = v * v;
      v = vsx[0]; P[1][1] = v * v;
      v = asx[0]; P[2][2] = v * v;
      v = psy[0]; P[3][3] = v * v;
      v = vsy[0]; P[4][4] = v * v;
      v = asy[0]; P[5][5] = v * v; }

    float h[NF];
    #pragma unroll
    for (int k = 0; k < NF; ++k) { h[k] = 0.0f; c_lds[k][tid] = 0.0f; }

    const int total = Thist + len_pred;
    for (int t = 0; t < total; ++t) {
        // ---- feat = tanh(cf_W @ X + cf_b) ----
        float feat[NF];
        #pragma unroll
        for (int f = 0; f < NF; ++f) {
            float s = cfb[f]
                + cfW[f * 6 + 0] * X0 + cfW[f * 6 + 1] * X1 + cfW[f * 6 + 2] * X2
                + cfW[f * 6 + 3] * X3 + cfW[f * 6 + 4] * X4 + cfW[f * 6 + 5] * X5;
            feat[f] = tanhft(s);
        }
        // ---- LSTM cell ----
        #pragma unroll 4
        for (int j = 0; j < NF; ++j) {
            float gi = bih[j]          + bhh[j];
            float gf = bih[NF + j]     + bhh[NF + j];
            float gg = bih[2 * NF + j] + bhh[2 * NF + j];
            float go = bih[3 * NF + j] + bhh[3 * NF + j];
            #pragma unroll
            for (int k = 0; k < NF; ++k) {
                float fk = feat[k], hk = h[k];
                gi += Wih[(j         ) * NF + k] * fk + Whh[(j         ) * NF + k] * hk;
                gf += Wih[(NF + j    ) * NF + k] * fk + Whh[(NF + j    ) * NF + k] * hk;
                gg += Wih[(2 * NF + j) * NF + k] * fk + Whh[(2 * NF + j) * NF + k] * hk;
                go += Wih[(3 * NF + j) * NF + k] * fk + Whh[(3 * NF + j) * NF + k] * hk;
            }
            float cj = c_lds[j][tid];
            float cn = sigm(gf) * cj + sigm(gi) * tanhft(gg);
            c_lds[j][tid] = cn;
            hn_lds[j][tid] = sigm(go) * tanhft(cn);
        }
        #pragma unroll
        for (int k = 0; k < NF; ++k) h[k] = hn_lds[k][tid];

        if (t < Thist) {
            // ---------- history step (filter with measurement) ----------
            float zx = hist[((size_t)(t + 1) * B + b) * 2 + 0];
            float zy = hist[((size_t)(t + 1) * B + b) * 2 + 1];
            // X = F X
            X0 = X0 + dt * X1 + hd * X2;  X1 = X1 + dt * X2;
            X3 = X3 + dt * X4 + hd * X5;  X4 = X4 + dt * X5;
            // P = F P F^T + Q_hist
            fpft(P);
            { const float qa[3] = {qa0, qa1, qa2};
              const float qb[3] = {qb3, qb4, qb5};
              #pragma unroll
              for (int i = 0; i < 3; ++i)
                  #pragma unroll
                  for (int j = 0; j < 3; ++j) {
                      P[i][j]         += qa[i] * qa[j];
                      P[3 + i][3 + j] += qb[i] * qb[j];
                  } }
            // innovation
            float y0 = zx - X0, y1 = zy - X3;
            float S00 = P[0][0] + R00, S01 = P[0][3] + R01;
            float S10 = P[3][0] + R01, S11 = P[3][3] + R11;
            float idet = 1.0f / (S00 * S11 - S01 * S10);
            float i00 =  S11 * idet, i01 = -S01 * idet;
            float i10 = -S10 * idet, i11 =  S00 * idet;
            float K0[6], K1[6];
            #pragma unroll
            for (int i = 0; i < 6; ++i) {
                K0[i] = P[i][0] * i00 + P[i][3] * i10;
                K1[i] = P[i][0] * i01 + P[i][3] * i11;
            }
            X0 += K0[0] * y0 + K1[0] * y1;
            X1 += K0[1] * y0 + K1[1] * y1;
            X2 += K0[2] * y0 + K1[2] * y1;
            X3 += K0[3] * y0 + K1[3] * y1;
            X4 += K0[4] * y0 + K1[4] * y1;
            X5 += K0[5] * y0 + K1[5] * y1;
            // Joseph form: P = (I-KH) P (I-KH)^T + K R K^T
            float M[6][6];
            #pragma unroll
            for (int i = 0; i < 6; ++i)
                #pragma unroll
                for (int j = 0; j < 6; ++j)
                    M[i][j] = P[i][j] - K0[i] * P[0][j] - K1[i] * P[3][j];
            #pragma unroll
            for (int i = 0; i < 6; ++i) {
                float kr0 = K0[i] * R00 + K1[i] * R01;
                float kr1 = K0[i] * R01 + K1[i] * R11;
                #pragma unroll
                for (int j = 0; j < 6; ++j)
                    P[i][j] = M[i][j] - M[i][0] * K0[j] - M[i][3] * K1[j]
                              + kr0 * K0[j] + kr1 * K1[j];
            }
        } else {
            // ---------- prediction step (control input, no measurement) ----------
            float cmd0 = cob[0], cmd1 = cob[1], cmd2 = cob[2], cmd3 = cob[3];
            #pragma unroll
            for (int k = 0; k < NF; ++k) {
                float hk = h[k];
                cmd0 += coW[0 * NF + k] * hk;
                cmd1 += coW[1 * NF + k] * hk;
                cmd2 += coW[2 * NF + k] * hk;
                cmd3 += coW[3 * NF + k] * hk;
            }
            // X = F X + B cmd[0:2]   (B == G numerically)
            X0 = X0 + dt * X1 + hd * X2 + g0 * cmd0;
            X1 = X1 + dt * X2 + g1 * cmd0;
            X2 = X2 + g2 * cmd0;
            X3 = X3 + dt * X4 + hd * X5 + g0 * cmd1;
            X4 = X4 + dt * X5 + g1 * cmd1;
            X5 = X5 + g2 * cmd1;
            // Q = (GtG cmd[2:4]) outer-product
            float Gs[6] = {ga0 * cmd2, ga1 * cmd2, ga2 * cmd2,
                           gb3 * cmd3, gb4 * cmd3, gb5 * cmd3};
            fpft(P);
            #pragma unroll
            for (int i = 0; i < 6; ++i)
                #pragma unroll
                for (int j = 0; j < 6; ++j)
                    P[i][j] += Gs[i] * Gs[j];
            // outputs: [mu_x, mu_y, sx, sy, rho]
            int tp = t - Thist;
            float sx = sqrtf(P[0][0]), sy = sqrtf(P[3][3]);
            float rho = (P[0][3] + P[3][0]) / (2.0f * sx * sy);
            size_t o = ((size_t)tp * B + b) * 5u;
            out[o + 0] = X0;
            out[o + 1] = X3;
            out[o + 2] = sx;
            out[o + 3] = sy;
            out[o + 4] = rho;
        }
    }
}

extern "C" void kernel_launch(void* const* d_in, const int* in_sizes, int n_in,
                              void* d_out, int out_size, void* d_ws, size_t ws_size,
                              hipStream_t stream) {
    const int T = 16;                       // hist.shape[0] from setup_inputs
    const int B = in_sizes[0] / (2 * T);    // 32768
    const int len_pred = out_size / (5 * B);// 25
    const int grid = (B + BLK - 1) / BLK;
    kalman_lstm<<<grid, BLK, 0, stream>>>(
        (const float*)d_in[0],  (const float*)d_in[1],  (const float*)d_in[2],
        (const float*)d_in[3],  (const float*)d_in[4],  (const float*)d_in[5],
        (const float*)d_in[6],  (const float*)d_in[7],  (const float*)d_in[8],
        (const float*)d_in[9],  (const float*)d_in[10], (const float*)d_in[11],
        (const float*)d_in[12], (const float*)d_in[13], (const float*)d_in[14],
        (const float*)d_in[15], (const float*)d_in[16], (const float*)d_in[17],
        (float*)d_out, B, T - 1, len_pred);
}

// Round 2
// 675.671 us; speedup vs baseline: 9.8448x; 9.8448x over previous
//
#include <hip/hip_runtime.h>
#include <math.h>

#define BLK 64
#define EPB 16            // elements per block (one wave)
#define NF 32

typedef __attribute__((ext_vector_type(8))) short s16x8;  // 8 bf16 = 4 VGPRs
typedef __attribute__((ext_vector_type(4))) float f32x4;

__device__ __forceinline__ float sigm(float x) {
    return __fdividef(1.0f, 1.0f + __expf(-x));
}
__device__ __forceinline__ float tanhft(float x) {
    float a = fabsf(x);
    float e = __expf(-2.0f * a);
    float t = __fdividef(1.0f - e, 1.0f + e);
    return copysignf(t, x);
}

__device__ __forceinline__ unsigned short bf16h(float x) {
    unsigned u = __float_as_uint(x);
    return (unsigned short)((u + 0x7FFFu + ((u >> 16) & 1u)) >> 16);
}
__device__ __forceinline__ float bf16tof(unsigned short h) {
    return __uint_as_float(((unsigned)h) << 16);
}
// split fp32 into hi+lo bf16 (~17-bit effective mantissa)
__device__ __forceinline__ void bsplit(float x, short& hi, short& lo) {
    unsigned short h = bf16h(x);
    hi = (short)h;
    lo = (short)bf16h(x - bf16tof(h));
}

// P = F P F^T for the constant-accel F (dt=0.2), in place
__device__ __forceinline__ void fpft(float (&P)[6][6]) {
    const float dt = 0.2f, hd = 0.02f;
    #pragma unroll
    for (int j = 0; j < 6; ++j) {
        float a0 = P[0][j] + dt * P[1][j] + hd * P[2][j];
        float a1 = P[1][j] + dt * P[2][j];
        float a3 = P[3][j] + dt * P[4][j] + hd * P[5][j];
        float a4 = P[4][j] + dt * P[5][j];
        P[0][j] = a0; P[1][j] = a1; P[3][j] = a3; P[4][j] = a4;
    }
    #pragma unroll
    for (int i = 0; i < 6; ++i) {
        float a0 = P[i][0] + dt * P[i][1] + hd * P[i][2];
        float a1 = P[i][1] + dt * P[i][2];
        float a3 = P[i][3] + dt * P[i][4] + hd * P[i][5];
        float a4 = P[i][4] + dt * P[i][5];
        P[i][0] = a0; P[i][1] = a1; P[i][3] = a3; P[i][4] = a4;
    }
}

#define GSTRIDE 21   // LDS gate buffer row stride (floats): <=2-way bank conflicts

__global__ __launch_bounds__(BLK, 2)
void kalman_lstm(const float* __restrict__ hist,
                 const float* __restrict__ psx, const float* __restrict__ psy,
                 const float* __restrict__ vsx, const float* __restrict__ vsy,
                 const float* __restrict__ asx, const float* __restrict__ asy,
                 const float* __restrict__ jerk, const float* __restrict__ coefG,
                 const float* __restrict__ GRv,
                 const float* __restrict__ cfW, const float* __restrict__ cfb,
                 const float* __restrict__ Wih, const float* __restrict__ Whh,
                 const float* __restrict__ bih, const float* __restrict__ bhh,
                 const float* __restrict__ coW, const float* __restrict__ cob,
                 float* __restrict__ out, int B, int Thist, int len_pred)
{
    __shared__ float gbuf[128 * GSTRIDE];   // [gate 0..127][elem 0..15], stride 21

    const int lane = threadIdx.x;
    const int e = lane & 15;        // element slot within block (A-frag m / combine elem)
    const int s = lane >> 4;        // quad: k-slice / feature-slice owner
    const int b = blockIdx.x * EPB + e;   // global batch element

    const float dt = 0.2f;
    const float hd = 0.02f;
    const float g0 = dt * dt * dt / 6.0f;
    const float g1 = 0.02f;
    const float g2 = dt;

    // ---- uniform precompute ----
    float gr0 = GRv[0], gr1 = GRv[1];
    float R00 = gr0 * gr0, R01 = gr0 * gr1, R11 = gr1 * gr1;
    float ga0 = g0 * tanhf(coefG[0]);
    float ga1 = g1 * tanhf(coefG[1]);
    float ga2 = g2 * tanhf(coefG[2]);
    float gb3 = g0 * tanhf(coefG[3]);
    float gb4 = g1 * tanhf(coefG[4]);
    float gb5 = g2 * tanhf(coefG[5]);
    float j0 = jerk[0], j1 = jerk[1];
    float qa[3] = {ga0 * j0, ga1 * j0, ga2 * j0};
    float qb[3] = {gb3 * j1, gb4 * j1, gb5 * j1};

    // ---- load LSTM weights once into register B-fragments (hi/lo bf16 split) ----
    // B-frag layout (16x16x32): lane holds B[k=s*8+j][n = nt*16 + (lane&15)], j=0..7
    s16x8 wih_h[8], wih_l[8], whh_h[8], whh_l[8];
    #pragma unroll
    for (int nt = 0; nt < 8; ++nt) {
        int row = nt * 16 + e;          // gate row 0..127
        int base = row * NF + s * 8;    // 8 consecutive k
        #pragma unroll
        for (int j = 0; j < 8; ++j) {
            short hi, lo;
            bsplit(Wih[base + j], hi, lo);
            wih_h[nt][j] = hi; wih_l[nt][j] = lo;
            bsplit(Whh[base + j], hi, lo);
            whh_h[nt][j] = hi; whh_l[nt][j] = lo;
        }
    }
    // per-lane gate bias (folded into MFMA accumulator init): gate col nt*16+e
    float bias8[8];
    #pragma unroll
    for (int nt = 0; nt < 8; ++nt) {
        int g = nt * 16 + e;
        bias8[nt] = bih[g] + bhh[g];
    }

    // ---- Kalman init (replicated across the 4 lanes of each element) ----
    const float2* hist2 = (const float2*)hist;
    float2 z0 = hist2[b];
    float2 z1 = hist2[B + b];
    float X0 = z0.x, X1 = (z1.x - z0.x) / dt, X2 = 0.0f;
    float X3 = (z1.y - z0.y) / dt, X4 = 0.0f, X5 = 0.0f;   // ref overwrites slot 3 with v0y

    float P[6][6];
    #pragma unroll
    for (int i = 0; i < 6; ++i)
        #pragma unroll
        for (int j = 0; j < 6; ++j) P[i][j] = 0.0f;
    { float v;
      v = psx[0]; P[0][0] = v * v;
      v = vsx[0]; P[1][1] = v * v;
      v = asx[0]; P[2][2] = v * v;
      v = psy[0]; P[3][3] = v * v;
      v = vsy[0]; P[4][4] = v * v;
      v = asy[0]; P[5][5] = v * v; }

    // LSTM state: lane owns features [8s, 8s+8) of its element
    float creg[8], hreg[8];
    #pragma unroll
    for (int j = 0; j < 8; ++j) { creg[j] = 0.0f; hreg[j] = 0.0f; }
    s16x8 ah_h = (s16x8)0, ah_l = (s16x8)0;   // h as A-fragment (zero init)

    const int total = Thist + len_pred;
    for (int t = 0; t < total; ++t) {
        // ---- feat slice: f = 8s+jj, from current X ----
        s16x8 af_h, af_l;
        #pragma unroll
        for (int jj = 0; jj < 8; ++jj) {
            int f = 8 * s + jj;
            float acc = cfb[f]
                + cfW[f * 6 + 0] * X0 + cfW[f * 6 + 1] * X1 + cfW[f * 6 + 2] * X2
                + cfW[f * 6 + 3] * X3 + cfW[f * 6 + 4] * X4 + cfW[f * 6 + 5] * X5;
            float fv = tanhft(acc);
            short hi, lo; bsplit(fv, hi, lo);
            af_h[jj] = hi; af_l[jj] = lo;
        }

        __syncthreads();   // WAR: previous iteration's gate reads done before overwrite

        // ---- gates = [feat|h] @ W^T via MFMA (hi/lo split: 3 products per matrix) ----
        #pragma unroll
        for (int nt = 0; nt < 8; ++nt) {
            f32x4 acc = {bias8[nt], bias8[nt], bias8[nt], bias8[nt]};
            acc = __builtin_amdgcn_mfma_f32_16x16x32_bf16(af_h, wih_h[nt], acc, 0, 0, 0);
            acc = __builtin_amdgcn_mfma_f32_16x16x32_bf16(af_l, wih_h[nt], acc, 0, 0, 0);
            acc = __builtin_amdgcn_mfma_f32_16x16x32_bf16(af_h, wih_l[nt], acc, 0, 0, 0);
            acc = __builtin_amdgcn_mfma_f32_16x16x32_bf16(ah_h, whh_h[nt], acc, 0, 0, 0);
            acc = __builtin_amdgcn_mfma_f32_16x16x32_bf16(ah_l, whh_h[nt], acc, 0, 0, 0);
            acc = __builtin_amdgcn_mfma_f32_16x16x32_bf16(ah_h, whh_l[nt], acc, 0, 0, 0);
            // C layout: col(gate) = lane&15, row(elem) = s*4 + reg
            int wbase = (nt * 16 + e) * GSTRIDE + s * 4;
            gbuf[wbase + 0] = acc[0];
            gbuf[wbase + 1] = acc[1];
            gbuf[wbase + 2] = acc[2];
            gbuf[wbase + 3] = acc[3];
        }

        __syncthreads();   // RAW: gates visible to all lanes

        // ---- combine: lane (e,s) handles features [8s,8s+8) of element e ----
        #pragma unroll
        for (int jj = 0; jj < 8; ++jj) {
            int f = 8 * s + jj;
            float gi = gbuf[(f)       * GSTRIDE + e];
            float gf = gbuf[(32 + f)  * GSTRIDE + e];
            float gg = gbuf[(64 + f)  * GSTRIDE + e];
            float go = gbuf[(96 + f)  * GSTRIDE + e];
            float cn = sigm(gf) * creg[jj] + sigm(gi) * tanhft(gg);
            creg[jj] = cn;
            float hn = sigm(go) * tanhft(cn);
            hreg[jj] = hn;
            short hi, lo; bsplit(hn, hi, lo);
            ah_h[jj] = hi; ah_l[jj] = lo;
        }

        if (t < Thist) {
            // ---------- history step: predict + measurement update ----------
            float2 z = hist2[(size_t)(t + 1) * B + b];
            X0 = X0 + dt * X1 + hd * X2;  X1 = X1 + dt * X2;
            X3 = X3 + dt * X4 + hd * X5;  X4 = X4 + dt * X5;
            fpft(P);
            #pragma unroll
            for (int i = 0; i < 3; ++i)
                #pragma unroll
                for (int j = 0; j < 3; ++j) {
                    P[i][j]         += qa[i] * qa[j];
                    P[3 + i][3 + j] += qb[i] * qb[j];
                }
            float y0 = z.x - X0, y1 = z.y - X3;
            float S00 = P[0][0] + R00, S01 = P[0][3] + R01;
            float S10 = P[3][0] + R01, S11 = P[3][3] + R11;
            float idet = 1.0f / (S00 * S11 - S01 * S10);
            float i00 =  S11 * idet, i01 = -S01 * idet;
            float i10 = -S10 * idet, i11 =  S00 * idet;
            float K0[6], K1[6];
            #pragma unroll
            for (int i = 0; i < 6; ++i) {
                K0[i] = P[i][0] * i00 + P[i][3] * i10;
                K1[i] = P[i][0] * i01 + P[i][3] * i11;
            }
            X0 += K0[0] * y0 + K1[0] * y1;
            X1 += K0[1] * y0 + K1[1] * y1;
            X2 += K0[2] * y0 + K1[2] * y1;
            X3 += K0[3] * y0 + K1[3] * y1;
            X4 += K0[4] * y0 + K1[4] * y1;
            X5 += K0[5] * y0 + K1[5] * y1;
            float M[6][6];
            #pragma unroll
            for (int i = 0; i < 6; ++i)
                #pragma unroll
                for (int j = 0; j < 6; ++j)
                    M[i][j] = P[i][j] - K0[i] * P[0][j] - K1[i] * P[3][j];
            #pragma unroll
            for (int i = 0; i < 6; ++i) {
                float kr0 = K0[i] * R00 + K1[i] * R01;
                float kr1 = K0[i] * R01 + K1[i] * R11;
                #pragma unroll
                for (int j = 0; j < 6; ++j)
                    P[i][j] = M[i][j] - M[i][0] * K0[j] - M[i][3] * K1[j]
                              + kr0 * K0[j] + kr1 * K1[j];
            }
        } else {
            // ---------- prediction step ----------
            // command = coW @ h + cob; partial over this lane's h slice, reduce over s
            float c0 = 0.0f, c1 = 0.0f, c2 = 0.0f, c3 = 0.0f;
            #pragma unroll
            for (int jj = 0; jj < 8; ++jj) {
                int f = 8 * s + jj;
                float hk = hreg[jj];
                c0 += coW[0 * NF + f] * hk;
                c1 += coW[1 * NF + f] * hk;
                c2 += coW[2 * NF + f] * hk;
                c3 += coW[3 * NF + f] * hk;
            }
            c0 += __shfl_xor(c0, 16, 64); c0 += __shfl_xor(c0, 32, 64);
            c1 += __shfl_xor(c1, 16, 64); c1 += __shfl_xor(c1, 32, 64);
            c2 += __shfl_xor(c2, 16, 64); c2 += __shfl_xor(c2, 32, 64);
            c3 += __shfl_xor(c3, 16, 64); c3 += __shfl_xor(c3, 32, 64);
            float cmd0 = c0 + cob[0], cmd1 = c1 + cob[1];
            float cmd2 = c2 + cob[2], cmd3 = c3 + cob[3];

            X0 = X0 + dt * X1 + hd * X2 + g0 * cmd0;
            X1 = X1 + dt * X2 + g1 * cmd0;
            X2 = X2 + g2 * cmd0;
            X3 = X3 + dt * X4 + hd * X5 + g0 * cmd1;
            X4 = X4 + dt * X5 + g1 * cmd1;
            X5 = X5 + g2 * cmd1;
            float Gs[6] = {ga0 * cmd2, ga1 * cmd2, ga2 * cmd2,
                           gb3 * cmd3, gb4 * cmd3, gb5 * cmd3};
            fpft(P);
            #pragma unroll
            for (int i = 0; i < 6; ++i)
                #pragma unroll
                for (int j = 0; j < 6; ++j)
                    P[i][j] += Gs[i] * Gs[j];

            int tp = t - Thist;
            float sx = sqrtf(P[0][0]), sy = sqrtf(P[3][3]);
            float rho = (P[0][3] + P[3][0]) / (2.0f * sx * sy);
            if (s == 0) {
                size_t o = ((size_t)tp * B + b) * 5u;
                out[o + 0] = X0;
                out[o + 1] = X3;
                out[o + 2] = sx;
                out[o + 3] = sy;
                out[o + 4] = rho;
            }
        }
    }
}

extern "C" void kernel_launch(void* const* d_in, const int* in_sizes, int n_in,
                              void* d_out, int out_size, void* d_ws, size_t ws_size,
                              hipStream_t stream) {
    const int T = 16;
    const int B = in_sizes[0] / (2 * T);      // 32768
    const int len_pred = out_size / (5 * B);  // 25
    const int grid = (B + EPB - 1) / EPB;     // one wave per 16 elements
    kalman_lstm<<<grid, BLK, 0, stream>>>(
        (const float*)d_in[0],  (const float*)d_in[1],  (const float*)d_in[2],
        (const float*)d_in[3],  (const float*)d_in[4],  (const float*)d_in[5],
        (const float*)d_in[6],  (const float*)d_in[7],  (const float*)d_in[8],
        (const float*)d_in[9],  (const float*)d_in[10], (const float*)d_in[11],
        (const float*)d_in[12], (const float*)d_in[13], (const float*)d_in[14],
        (const float*)d_in[15], (const float*)d_in[16], (const float*)d_in[17],
        (float*)d_out, B, T - 1, len_pred);
}